// Round 13
// baseline (1121.006 us; speedup 1.0000x reference)
//
#include <hip/hip_runtime.h>

#define T_STEPS 512
#define BATCH   256
#define DIN     256
#define DHID    256
#define NWG     256      // one WG per batch row
#define NTHREADS 512     // 8 waves: wave = (gate, n-half), 2 waves/SIMD

typedef short bf16_t;
typedef __attribute__((ext_vector_type(4))) short short4v;
typedef __attribute__((ext_vector_type(8))) short short8;
typedef __attribute__((ext_vector_type(4))) float f32x4;
typedef __attribute__((ext_vector_type(4))) int int32x4;
typedef unsigned int uint;
typedef unsigned short ushort;

// ---- workspace layout (bytes) ----
#define WS_WXP  0u                   // 512 KB bf16 Wx frags
#define WS_WHQ  (512u << 10)         // 256 KB i8 Wh frags
#define WS_SW   (768u << 10)         // 4 KB f32 sW[1024] (amax/(127*32512))
#define WS_RQ   (772u << 10)         // 4 KB f32 rq[1024] (127/amax)
#define WS_BIAS (776u << 10)         // 4 KB
#define WS_TMP  (780u << 10)         // 16 B
#define WS_HGQ  (784u << 10)         // 128 KB h state: hi plane + lo plane
#define WS_CG   (912u << 10)         // 256 KB f32 c state
#define WS_THX  (2u << 20)           // CH*512KB theta_x chunk (f16)

#define TXSTEPU 131072               // uints per t: 256 rows x 4 gates x 128
#define HSCALE  32512.f              // 127*256

__device__ inline short f2bf(float f) {
  union { float f; uint u; } v; v.f = f;
  uint r = (v.u + 0x7FFFu + ((v.u >> 16) & 1u)) >> 16;
  return (short)r;
}
__device__ inline ushort f2h(float f) {
  union { _Float16 h; ushort u; } v; v.h = (_Float16)f; return v.u;
}
__device__ inline float h2f(ushort u) {
  union { _Float16 h; ushort u; } v; v.u = u; return (float)v.h;
}
__device__ inline float frcp(float x) { return __builtin_amdgcn_rcpf(x); }
__device__ inline float fast_sigmoid(float x) { return frcp(1.f + __expf(-x)); }
__device__ inline float fast_tanh(float x) {
  float ax = fabsf(x);
  float e = __expf(2.f * ax);              // inf-safe
  float r = 1.f - 2.f * frcp(e + 1.f);
  return copysignf(r, x);
}

// asm i8 MFMA with B pinned in AGPRs (r5..r11-proven: chains bookended by
// builtins so the compiler guards VALU<->MFMA hazards).
__device__ inline void mfma_i8_a(int32x4& acc, int32x4 a, int32x4 b) {
  asm("v_mfma_i32_16x16x64_i8 %0, %1, %2, %0"
      : "+v"(acc) : "v"(a), "a"(b));
}

// DPP fetch with multiplicative identity for invalid/masked lanes.
#define DPPM(x, ctrl, rmask)                                                  \
  __int_as_float(__builtin_amdgcn_update_dpp(                                 \
      0x3f800000, __float_as_int(x), (ctrl), (rmask), 0xf, false))

// ---- per-neuron amax scales for Wh (k in [256,512)) ----
// sw = amax/(127*32512): dequant for W (x127/amax) and h16 (x32512) quant.
__global__ __launch_bounds__(256) void k_scales(
    const float* __restrict__ Wf, const float* __restrict__ Wi,
    const float* __restrict__ Wg, const float* __restrict__ Wo,
    float* __restrict__ sw, float* __restrict__ rq)
{
  int n = blockIdx.x * 256 + threadIdx.x;       // 0..1023
  int gate = n >> 8, nrow = n & 255;
  const float* W = gate == 0 ? Wf : gate == 1 ? Wi : gate == 2 ? Wg : Wo;
  const float4* row = (const float4*)(W + (size_t)nrow * 512 + 256);
  float amax = 0.f;
#pragma unroll 4
  for (int k = 0; k < 64; ++k) {
    float4 v = row[k];
    amax = fmaxf(amax, fmaxf(fmaxf(fabsf(v.x), fabsf(v.y)),
                             fmaxf(fabsf(v.z), fabsf(v.w))));
  }
  sw[n] = amax / (127.f * HSCALE);
  rq[n] = amax > 0.f ? 127.f / amax : 0.f;
}

// ---- pack Wx (k<256) into bf16 MFMA B-frag order + bias + temps ----
__global__ __launch_bounds__(256) void k_packx(
    const float* __restrict__ Wf, const float* __restrict__ Wi,
    const float* __restrict__ Wg, const float* __restrict__ Wo,
    const float* __restrict__ bf_, const float* __restrict__ bi_,
    const float* __restrict__ bg_, const float* __restrict__ bo_,
    const float* __restrict__ tf_, const float* __restrict__ ti_,
    const float* __restrict__ tg_, const float* __restrict__ to_,
    bf16_t* __restrict__ Wxp, float* __restrict__ bias,
    float* __restrict__ temps)
{
  int tid = blockIdx.x * 256 + threadIdx.x;     // 0..32767
  int nt = tid >> 9;
  int kt = (tid >> 6) & 7;
  int lane = tid & 63;
  int n = nt * 16 + (lane & 15);
  int gate = n >> 8, nrow = n & 255;
  int k = kt * 32 + (lane >> 4) * 8;
  const float* W = gate == 0 ? Wf : gate == 1 ? Wi : gate == 2 ? Wg : Wo;
  const float* src = W + (size_t)nrow * 512 + k;
  short8 d;
#pragma unroll
  for (int j = 0; j < 8; ++j) d[j] = f2bf(src[j]);
  *(short8*)(Wxp + (size_t)tid * 8) = d;

  if (tid < 1024) {
    int g2 = tid >> 8;
    const float* bs = g2 == 0 ? bf_ : g2 == 1 ? bi_ : g2 == 2 ? bg_ : bo_;
    bias[tid] = bs[tid & 255];
  }
  if (tid < 4) {
    const float* ts = tid == 0 ? tf_ : tid == 1 ? ti_ : tid == 2 ? tg_ : to_;
    temps[tid] = ts[0];
  }
}

// ---- pack Wh into i8 16x16x64 B-frag order with scan-friendly n-perm ----
// ntile nt = g*16 + hh*8 + j, frag col fc: neuron kk(within gate) =
// hh*128 + (j>>1)*32 + fc*2 + (j&1)  -> rec lane L holds kk pair {2L, 2L+1}.
__global__ __launch_bounds__(256) void k_packh(
    const float* __restrict__ Wf, const float* __restrict__ Wi,
    const float* __restrict__ Wg, const float* __restrict__ Wo,
    const float* __restrict__ rq, signed char* __restrict__ Whq)
{
  int tid = blockIdx.x * 256 + threadIdx.x;     // 0..16383
  int nt = tid >> 8;
  int kt = (tid >> 6) & 3;
  int lane = tid & 63;
  int fc = lane & 15;
  int gate = nt >> 4, hh = (nt >> 3) & 1, j = nt & 7;
  int n = gate * 256 + hh * 128 + ((j >> 1) << 5) + fc * 2 + (j & 1);
  int nrow = n & 255;
  int k0 = 256 + kt * 64 + (lane >> 4) * 16;
  const float* W = gate == 0 ? Wf : gate == 1 ? Wi : gate == 2 ? Wg : Wo;
  const float* src = W + (size_t)nrow * 512 + k0;
  float r = rq[n];
  union { signed char b[16]; int32x4 v; } pk;
#pragma unroll
  for (int jj = 0; jj < 16; ++jj) {
    int qi = __float2int_rn(src[jj] * r);
    qi = qi > 127 ? 127 : (qi < -127 ? -127 : qi);
    pk.b[jj] = (signed char)qi;
  }
  *(int32x4*)(Whq + (size_t)tid * 16) = pk.v;
}

// ---- theta_x GEMM; store f16 ushort[t][row256][gate4][kk256] ----
__global__ __launch_bounds__(256, 1) void gemm_thx(
    const float* __restrict__ x,        // chunk slice [CH*256, 256]
    const bf16_t* __restrict__ Wxp,
    const float* __restrict__ bias,
    ushort* __restrict__ thxH)
{
  __shared__ bf16_t Ax[64 * 256];       // XOR-swizzled, 512 B row stride
  const int tid = threadIdx.x;
  const int wave = tid >> 6, lane = tid & 63;
  const int lg = lane >> 4, c = lane & 15;
  const int mb = blockIdx.x * 64;

#pragma unroll
  for (int rep = 0; rep < 16; ++rep) {
    int idx = tid + rep * 256;
    int row = idx >> 6, c4f = (idx & 63) * 4;
    float4 v = *(const float4*)(x + (size_t)(mb + row) * 256 + c4f);
    short4v d;
    d[0] = f2bf(v.x); d[1] = f2bf(v.y); d[2] = f2bf(v.z); d[3] = f2bf(v.w);
    *(short4v*)((char*)Ax + row * 512 + ((c4f * 2) ^ ((row & 7) << 4))) = d;
  }
  __syncthreads();

  short8 af[4][8];
#pragma unroll
  for (int mf = 0; mf < 4; ++mf)
#pragma unroll
    for (int kt = 0; kt < 8; ++kt) {
      int row = mf * 16 + (lane & 15);
      int kb = kt * 64 + (lane >> 4) * 16;
      af[mf][kt] = *(const short8*)((char*)Ax + row * 512 + (kb ^ ((row & 7) << 4)));
    }

#pragma unroll 1
  for (int i = 0; i < 16; ++i) {
    short8 wfr[8];
#pragma unroll
    for (int kt = 0; kt < 8; ++kt)
      wfr[kt] = *(const short8*)(Wxp + ((((size_t)(wave * 16 + i)) * 8 + kt) * 64 + lane) * 8);
    float bv = bias[wave * 256 + i * 16 + c];
    f32x4 ac[4];
#pragma unroll
    for (int mf = 0; mf < 4; ++mf) ac[mf] = (f32x4){0.f, 0.f, 0.f, 0.f};
#pragma unroll
    for (int kt = 0; kt < 8; ++kt)
#pragma unroll
      for (int mf = 0; mf < 4; ++mf)
        ac[mf] = __builtin_amdgcn_mfma_f32_16x16x32_bf16(af[mf][kt], wfr[kt], ac[mf], 0, 0, 0);
    const int kkg = i * 16 + c;
#pragma unroll
    for (int mf = 0; mf < 4; ++mf)
#pragma unroll
      for (int r = 0; r < 4; ++r) {
        int mrow = mb + mf * 16 + lg * 4 + r;
        int trel = mrow >> 8, rw = mrow & 255;
        thxH[(((size_t)trel * 256 + rw) * 4 + wave) * 256 + kkg] =
            f2h(ac[mf][r] + bv);
      }
  }
}

// ---- Recurrent kernel: 256 WGs (1 row each) x 512 thr, 2 waves/SIMD.
// Wave (g,hh): 8 ntiles x 4 kt i8 frags (kt0,3 VGPR / kt1,2 AGPR).
// h state = 16-bit (hi/lo i8 planes, two MFMA chains, exact int combine).
// Broadcast-A from 512B Hq buffer; DPP scan; 2 barriers/step.
__global__ __launch_bounds__(NTHREADS, 2) void qlstm_rec(
    const uint* __restrict__ thxU,
    const int32x4* __restrict__ Whq,
    const float* __restrict__ sw,
    const float* __restrict__ temps,
    signed char* __restrict__ hGq, float* __restrict__ cG,
    float* __restrict__ out,
    int t0, int nsteps)
{
  __shared__ signed char Hq[512];             // h(t): hi plane [0,256), lo [256,512)
  __shared__ float RAW[4 * 264];              // raw cumprods [gate][kk]
  __shared__ __align__(16) float halfTot[4];  // half-0 totals per gate

  const int tid = threadIdx.x;
  const int wv = tid >> 6, lane = tid & 63;
  const int g = wv >> 1, hh = wv & 1;
  const int lg = lane >> 4;
  const int row = blockIdx.x;
  const int ukk = tid & 255, e = tid >> 8;

  // ---- Wh frags: kt0,3 -> VGPR (builtin bookends), kt1,2 -> AGPR (asm) ----
  int32x4 w0[8], w3[8], wa1[8], wa2[8];
#pragma unroll
  for (int j = 0; j < 8; ++j) {
    const size_t nb = (size_t)(g * 16 + hh * 8 + j) * 4;
    w0[j]  = Whq[(nb + 0) * 64 + lane];
    wa1[j] = Whq[(nb + 1) * 64 + lane];
    wa2[j] = Whq[(nb + 2) * 64 + lane];
    w3[j]  = Whq[(nb + 3) * 64 + lane];
  }
  const float2 sc = *(const float2*)&sw[g * 256 + hh * 128 + lane * 2];
  const float it0 = frcp(temps[0]), it1 = frcp(temps[1]);
  const float it2 = frcp(temps[2]), it3 = frcp(temps[3]);

  // ---- init h / c ----
  float creg = 0.f;
  {
    signed char hvh = 0, hvl = 0;
    if (t0 != 0) {
      hvh = hGq[(size_t)row * 256 + ukk];
      hvl = hGq[65536 + (size_t)row * 256 + ukk];
      creg = cG[(size_t)row * 256 + ukk];
    }
    if (e == 0) { Hq[ukk] = hvh; Hq[256 + ukk] = hvl; }
  }
  __syncthreads();

  const size_t txbase = ((size_t)row * 4 + g) * 128 + hh * 64 + lane;
  uint tx = thxU[txbase];
  float hprev = 0.f, cprev = 0.f;

#pragma unroll 1
  for (int ts = 0; ts < nsteps; ++ts) {
    const int t = t0 + ts;

    // deferred h(t-1) store: drains during GEMM, not at a barrier
    if (ts > 0 && e == 0)
      out[((size_t)(t - 1) * BATCH + row) * DHID + ukk] = hprev;

    // prefetch theta_x(ts+1)
    const int tsn = (ts + 1 < nsteps) ? ts + 1 : ts;
    const uint txn = thxU[(size_t)tsn * TXSTEPU + txbase];

    // A-frags: broadcast reads (all M rows = replicas for free)
    int32x4 afh0 = *(const int32x4*)&Hq[lg * 16];
    int32x4 afh1 = *(const int32x4*)&Hq[lg * 16 + 64];
    int32x4 afh2 = *(const int32x4*)&Hq[lg * 16 + 128];
    int32x4 afh3 = *(const int32x4*)&Hq[lg * 16 + 192];
    int32x4 afl0 = *(const int32x4*)&Hq[256 + lg * 16];
    int32x4 afl1 = *(const int32x4*)&Hq[256 + lg * 16 + 64];
    int32x4 afl2 = *(const int32x4*)&Hq[256 + lg * 16 + 128];
    int32x4 afl3 = *(const int32x4*)&Hq[256 + lg * 16 + 192];

    // GEMM: two i8 chains (hi, lo), shared W frags, 64 MFMA/wave
    const int32x4 zq = {0, 0, 0, 0};
    int32x4 acch[8], accl[8];
#pragma unroll
    for (int j = 0; j < 8; ++j)
      acch[j] = __builtin_amdgcn_mfma_i32_16x16x64_i8(afh0, w0[j], zq, 0, 0, 0);
#pragma unroll
    for (int j = 0; j < 8; ++j)
      accl[j] = __builtin_amdgcn_mfma_i32_16x16x64_i8(afl0, w0[j], zq, 0, 0, 0);
#pragma unroll
    for (int j = 0; j < 8; ++j) mfma_i8_a(acch[j], afh1, wa1[j]);
#pragma unroll
    for (int j = 0; j < 8; ++j) mfma_i8_a(accl[j], afl1, wa1[j]);
#pragma unroll
    for (int j = 0; j < 8; ++j) mfma_i8_a(acch[j], afh2, wa2[j]);
#pragma unroll
    for (int j = 0; j < 8; ++j) mfma_i8_a(accl[j], afl2, wa2[j]);
#pragma unroll
    for (int j = 0; j < 8; ++j)
      acch[j] = __builtin_amdgcn_mfma_i32_16x16x64_i8(afh3, w3[j], acch[j], 0, 0, 0);
#pragma unroll
    for (int j = 0; j < 8; ++j)
      accl[j] = __builtin_amdgcn_mfma_i32_16x16x64_i8(afl3, w3[j], accl[j], 0, 0, 0);

    // select this lane's kk pair {2L,2L+1}, exact int combine, dequant, cos
    int ah0 = (lg < 2) ? (lg == 0 ? acch[0][0] : acch[2][0])
                       : (lg == 2 ? acch[4][0] : acch[6][0]);
    int ah1 = (lg < 2) ? (lg == 0 ? acch[1][0] : acch[3][0])
                       : (lg == 2 ? acch[5][0] : acch[7][0]);
    int al0 = (lg < 2) ? (lg == 0 ? accl[0][0] : accl[2][0])
                       : (lg == 2 ? accl[4][0] : accl[6][0]);
    int al1 = (lg < 2) ? (lg == 0 ? accl[1][0] : accl[3][0])
                       : (lg == 2 ? accl[5][0] : accl[7][0]);
    float th0 = (float)((ah0 << 8) + al0) * sc.x;
    float th1 = (float)((ah1 << 8) + al1) * sc.y;
    float c0 = __cosf(h2f((ushort)(tx & 0xffffu)) + th0);
    float c1 = __cosf(h2f((ushort)(tx >> 16)) + th1);
    float pair = c0 * c1;

    // DPP 64-lane inclusive multiply-scan (row_shr 1,2,4,8 + bcast15/31)
    float s = pair;
    s *= DPPM(s, 0x111, 0xf);
    s *= DPPM(s, 0x112, 0xf);
    s *= DPPM(s, 0x114, 0xf);
    s *= DPPM(s, 0x118, 0xf);
    s *= DPPM(s, 0x142, 0xa);
    s *= DPPM(s, 0x143, 0xc);
    const float incl = s;
    float prefix = __shfl_up(incl, 1);
    if (lane == 0) prefix = 1.f;

    // publish raw cumprods (half-local); halfTot correction done in update
    float2 rw; rw.x = prefix * c0; rw.y = incl;
    *(float2*)&RAW[g * 264 + hh * 128 + lane * 2] = rw;
    if (hh == 0 && lane == 63) halfTot[g] = incl;
    __syncthreads();   // B1: RAW + halfTot complete

    // update: all 512 threads (e=0/1 duplicate compute; e=0 does I/O)
    {
      float r_f = RAW[0 * 264 + ukk], r_i = RAW[1 * 264 + ukk];
      float r_g = RAW[2 * 264 + ukk], r_o = RAW[3 * 264 + ukk];
      if (ukk >= 128) {                       // wave-uniform branch
        float4 hT = *(const float4*)halfTot;  // broadcast b128
        r_f *= hT.x; r_i *= hT.y; r_g *= hT.z; r_o *= hT.w;
      }
      float fv = fast_sigmoid(r_f * it0);
      float iv = fast_sigmoid(r_i * it1);
      float gv = fast_tanh  (r_g * it2);
      float ov = fast_sigmoid(r_o * it3);
      float cn = fv * creg + iv * gv;
      creg = cn;
      float h = ov * fast_tanh(cn);
      if (e == 0) {
        int q = __float2int_rn(h * HSCALE);
        int lo = ((q + 128) & 255) - 128;
        int hi = (q - lo) >> 8;
        Hq[ukk] = (signed char)hi;
        Hq[256 + ukk] = (signed char)lo;
        hprev = h; cprev = cn;
      }
    }
    __syncthreads();   // B2: Hq(t+1) complete

    tx = txn;
  }

  // epilogue: final h store + hx/cx + chunk state
  if (e == 0) {
    const int tl = t0 + nsteps - 1;
    out[((size_t)tl * BATCH + row) * DHID + ukk] = hprev;
    if (tl == T_STEPS - 1) {
      out[((size_t)T_STEPS * BATCH + row) * DHID + ukk] = hprev;
      out[((size_t)T_STEPS * BATCH + BATCH + row) * DHID + ukk] = cprev;
    }
    int q = __float2int_rn(hprev * HSCALE);
    int lo = ((q + 128) & 255) - 128;
    int hi = (q - lo) >> 8;
    hGq[(size_t)row * 256 + ukk] = (signed char)hi;
    hGq[65536 + (size_t)row * 256 + ukk] = (signed char)lo;
    cG[(size_t)row * 256 + ukk] = cprev;
  }
}

extern "C" void kernel_launch(void* const* d_in, const int* in_sizes, int n_in,
                              void* d_out, int out_size, void* d_ws, size_t ws_size,
                              hipStream_t stream) {
  (void)in_sizes; (void)n_in; (void)out_size;
  const float* x   = (const float*)d_in[0];
  const float* Wf  = (const float*)d_in[1];
  const float* bf_ = (const float*)d_in[2];
  const float* tf_ = (const float*)d_in[3];
  const float* Wi  = (const float*)d_in[4];
  const float* bi_ = (const float*)d_in[5];
  const float* ti_ = (const float*)d_in[6];
  const float* Wg  = (const float*)d_in[7];
  const float* bg_ = (const float*)d_in[8];
  const float* tg_ = (const float*)d_in[9];
  const float* Wo  = (const float*)d_in[10];
  const float* bo_ = (const float*)d_in[11];
  const float* to_ = (const float*)d_in[12];

  char* ws = (char*)d_ws;
  bf16_t*      Wxp   = (bf16_t*)(ws + WS_WXP);
  signed char* Whq   = (signed char*)(ws + WS_WHQ);
  float*       sw    = (float*)(ws + WS_SW);
  float*       rq    = (float*)(ws + WS_RQ);
  float*       bias  = (float*)(ws + WS_BIAS);
  float*       temps = (float*)(ws + WS_TMP);
  signed char* hGq   = (signed char*)(ws + WS_HGQ);
  float*       cG    = (float*)(ws + WS_CG);
  ushort*      thxH  = (ushort*)(ws + WS_THX);

  size_t avail = ws_size > (size_t)(2u << 20) ? ws_size - (size_t)(2u << 20) : 0;
  int CH = 4;
  const int cands[6] = {128, 64, 32, 16, 8, 4};
  for (int ci = 0; ci < 6; ++ci)
    if ((size_t)cands[ci] * 512 * 1024 <= avail) { CH = cands[ci]; break; }

  hipLaunchKernelGGL(k_scales, dim3(4), dim3(256), 0, stream,
                     Wf, Wi, Wg, Wo, sw, rq);
  hipLaunchKernelGGL(k_packx, dim3(128), dim3(256), 0, stream,
                     Wf, Wi, Wg, Wo, bf_, bi_, bg_, bo_, tf_, ti_, tg_, to_,
                     Wxp, bias, temps);
  hipLaunchKernelGGL(k_packh, dim3(64), dim3(256), 0, stream,
                     Wf, Wi, Wg, Wo, rq, Whq);

  for (int c0 = 0; c0 < T_STEPS; c0 += CH) {
    hipLaunchKernelGGL(gemm_thx, dim3(CH * 4), dim3(256), 0, stream,
                       x + (size_t)c0 * BATCH * DIN, Wxp, bias, thxH);
    hipLaunchKernelGGL(qlstm_rec, dim3(NWG), dim3(NTHREADS), 0, stream,
                       (const uint*)thxH, (const int32x4*)Whq, sw, temps,
                       hGq, cG, (float*)d_out, c0, CH);
  }
}

// Round 14
// 1117.167 us; speedup vs baseline: 1.0034x; 1.0034x over previous
//
#include <hip/hip_runtime.h>

#define T_STEPS 512
#define BATCH   256
#define DIN     256
#define DHID    256
#define NWG     256      // one WG per batch row
#define NTHREADS 512     // 8 waves: wave = (gate, n-half), 2 waves/SIMD

typedef short bf16_t;
typedef __attribute__((ext_vector_type(4))) short short4v;
typedef __attribute__((ext_vector_type(8))) short short8;
typedef __attribute__((ext_vector_type(4))) float f32x4;
typedef __attribute__((ext_vector_type(4))) int int32x4;
typedef unsigned int uint;
typedef unsigned short ushort;

// ---- workspace layout (bytes) ----
#define WS_WXP  0u                   // 512 KB bf16 Wx frags
#define WS_WHQ  (512u << 10)         // 256 KB i8 Wh frags
#define WS_SW   (768u << 10)         // 4 KB f32 sW[1024] (amax/(127*32512))
#define WS_RQ   (772u << 10)         // 4 KB f32 rq[1024] (127/amax)
#define WS_BIAS (776u << 10)         // 4 KB
#define WS_TMP  (780u << 10)         // 16 B
#define WS_HGQ  (784u << 10)         // 128 KB h state: hi plane + lo plane
#define WS_CG   (912u << 10)         // 256 KB f32 c state
#define WS_THX  (2u << 20)           // CH*512KB theta_x chunk (f16)

#define TXSTEPU 131072               // uints per t: 256 rows x 4 gates x 128
#define HSCALE  32512.f              // 127*256

__device__ inline short f2bf(float f) {
  union { float f; uint u; } v; v.f = f;
  uint r = (v.u + 0x7FFFu + ((v.u >> 16) & 1u)) >> 16;
  return (short)r;
}
__device__ inline ushort f2h(float f) {
  union { _Float16 h; ushort u; } v; v.h = (_Float16)f; return v.u;
}
__device__ inline float h2f(ushort u) {
  union { _Float16 h; ushort u; } v; v.u = u; return (float)v.h;
}
__device__ inline float frcp(float x) { return __builtin_amdgcn_rcpf(x); }
__device__ inline float fast_sigmoid(float x) { return frcp(1.f + __expf(-x)); }
__device__ inline float fast_tanh(float x) {
  float ax = fabsf(x);
  float e = __expf(2.f * ax);              // inf-safe
  float r = 1.f - 2.f * frcp(e + 1.f);
  return copysignf(r, x);
}

// asm i8 MFMA with B pinned in AGPRs (r5..r11-proven: chains bookended by
// builtins so the compiler guards VALU<->MFMA hazards).
__device__ inline void mfma_i8_a(int32x4& acc, int32x4 a, int32x4 b) {
  asm("v_mfma_i32_16x16x64_i8 %0, %1, %2, %0"
      : "+v"(acc) : "v"(a), "a"(b));
}

// DPP fetch with multiplicative identity for invalid/masked lanes.
#define DPPM(x, ctrl, rmask)                                                  \
  __int_as_float(__builtin_amdgcn_update_dpp(                                 \
      0x3f800000, __float_as_int(x), (ctrl), (rmask), 0xf, false))

// ---- per-neuron amax scales for Wh (k in [256,512)) ----
// sw = amax/(127*32512): dequant for W (x127/amax) and h16 (x32512) quant.
__global__ __launch_bounds__(256) void k_scales(
    const float* __restrict__ Wf, const float* __restrict__ Wi,
    const float* __restrict__ Wg, const float* __restrict__ Wo,
    float* __restrict__ sw, float* __restrict__ rq)
{
  int n = blockIdx.x * 256 + threadIdx.x;       // 0..1023
  int gate = n >> 8, nrow = n & 255;
  const float* W = gate == 0 ? Wf : gate == 1 ? Wi : gate == 2 ? Wg : Wo;
  const float4* row = (const float4*)(W + (size_t)nrow * 512 + 256);
  float amax = 0.f;
#pragma unroll 4
  for (int k = 0; k < 64; ++k) {
    float4 v = row[k];
    amax = fmaxf(amax, fmaxf(fmaxf(fabsf(v.x), fabsf(v.y)),
                             fmaxf(fabsf(v.z), fabsf(v.w))));
  }
  sw[n] = amax / (127.f * HSCALE);
  rq[n] = amax > 0.f ? 127.f / amax : 0.f;
}

// ---- pack Wx (k<256) into bf16 MFMA B-frag order + bias + temps ----
__global__ __launch_bounds__(256) void k_packx(
    const float* __restrict__ Wf, const float* __restrict__ Wi,
    const float* __restrict__ Wg, const float* __restrict__ Wo,
    const float* __restrict__ bf_, const float* __restrict__ bi_,
    const float* __restrict__ bg_, const float* __restrict__ bo_,
    const float* __restrict__ tf_, const float* __restrict__ ti_,
    const float* __restrict__ tg_, const float* __restrict__ to_,
    bf16_t* __restrict__ Wxp, float* __restrict__ bias,
    float* __restrict__ temps)
{
  int tid = blockIdx.x * 256 + threadIdx.x;     // 0..32767
  int nt = tid >> 9;
  int kt = (tid >> 6) & 7;
  int lane = tid & 63;
  int n = nt * 16 + (lane & 15);
  int gate = n >> 8, nrow = n & 255;
  int k = kt * 32 + (lane >> 4) * 8;
  const float* W = gate == 0 ? Wf : gate == 1 ? Wi : gate == 2 ? Wg : Wo;
  const float* src = W + (size_t)nrow * 512 + k;
  short8 d;
#pragma unroll
  for (int j = 0; j < 8; ++j) d[j] = f2bf(src[j]);
  *(short8*)(Wxp + (size_t)tid * 8) = d;

  if (tid < 1024) {
    int g2 = tid >> 8;
    const float* bs = g2 == 0 ? bf_ : g2 == 1 ? bi_ : g2 == 2 ? bg_ : bo_;
    bias[tid] = bs[tid & 255];
  }
  if (tid < 4) {
    const float* ts = tid == 0 ? tf_ : tid == 1 ? ti_ : tid == 2 ? tg_ : to_;
    temps[tid] = ts[0];
  }
}

// ---- pack Wh into i8 16x16x64 B-frag order with scan-friendly n-perm ----
// ntile nt = g*16 + hh*8 + j, frag col fc: neuron kk(within gate) =
// hh*128 + (j>>1)*32 + fc*2 + (j&1)  -> rec lane L holds kk pair {2L, 2L+1}.
__global__ __launch_bounds__(256) void k_packh(
    const float* __restrict__ Wf, const float* __restrict__ Wi,
    const float* __restrict__ Wg, const float* __restrict__ Wo,
    const float* __restrict__ rq, signed char* __restrict__ Whq)
{
  int tid = blockIdx.x * 256 + threadIdx.x;     // 0..16383
  int nt = tid >> 8;
  int kt = (tid >> 6) & 3;
  int lane = tid & 63;
  int fc = lane & 15;
  int gate = nt >> 4, hh = (nt >> 3) & 1, j = nt & 7;
  int n = gate * 256 + hh * 128 + ((j >> 1) << 5) + fc * 2 + (j & 1);
  int nrow = n & 255;
  int k0 = 256 + kt * 64 + (lane >> 4) * 16;
  const float* W = gate == 0 ? Wf : gate == 1 ? Wi : gate == 2 ? Wg : Wo;
  const float* src = W + (size_t)nrow * 512 + k0;
  float r = rq[n];
  union { signed char b[16]; int32x4 v; } pk;
#pragma unroll
  for (int jj = 0; jj < 16; ++jj) {
    int qi = __float2int_rn(src[jj] * r);
    qi = qi > 127 ? 127 : (qi < -127 ? -127 : qi);
    pk.b[jj] = (signed char)qi;
  }
  *(int32x4*)(Whq + (size_t)tid * 16) = pk.v;
}

// ---- theta_x GEMM; store f16 ushort[t][row256][gate4][kk256] ----
__global__ __launch_bounds__(256, 1) void gemm_thx(
    const float* __restrict__ x,        // chunk slice [CH*256, 256]
    const bf16_t* __restrict__ Wxp,
    const float* __restrict__ bias,
    ushort* __restrict__ thxH)
{
  __shared__ bf16_t Ax[64 * 256];       // XOR-swizzled, 512 B row stride
  const int tid = threadIdx.x;
  const int wave = tid >> 6, lane = tid & 63;
  const int lg = lane >> 4, c = lane & 15;
  const int mb = blockIdx.x * 64;

#pragma unroll
  for (int rep = 0; rep < 16; ++rep) {
    int idx = tid + rep * 256;
    int row = idx >> 6, c4f = (idx & 63) * 4;
    float4 v = *(const float4*)(x + (size_t)(mb + row) * 256 + c4f);
    short4v d;
    d[0] = f2bf(v.x); d[1] = f2bf(v.y); d[2] = f2bf(v.z); d[3] = f2bf(v.w);
    *(short4v*)((char*)Ax + row * 512 + ((c4f * 2) ^ ((row & 7) << 4))) = d;
  }
  __syncthreads();

  short8 af[4][8];
#pragma unroll
  for (int mf = 0; mf < 4; ++mf)
#pragma unroll
    for (int kt = 0; kt < 8; ++kt) {
      int row = mf * 16 + (lane & 15);
      int kb = kt * 64 + (lane >> 4) * 16;
      af[mf][kt] = *(const short8*)((char*)Ax + row * 512 + (kb ^ ((row & 7) << 4)));
    }

#pragma unroll 1
  for (int i = 0; i < 16; ++i) {
    short8 wfr[8];
#pragma unroll
    for (int kt = 0; kt < 8; ++kt)
      wfr[kt] = *(const short8*)(Wxp + ((((size_t)(wave * 16 + i)) * 8 + kt) * 64 + lane) * 8);
    float bv = bias[wave * 256 + i * 16 + c];
    f32x4 ac[4];
#pragma unroll
    for (int mf = 0; mf < 4; ++mf) ac[mf] = (f32x4){0.f, 0.f, 0.f, 0.f};
#pragma unroll
    for (int kt = 0; kt < 8; ++kt)
#pragma unroll
      for (int mf = 0; mf < 4; ++mf)
        ac[mf] = __builtin_amdgcn_mfma_f32_16x16x32_bf16(af[mf][kt], wfr[kt], ac[mf], 0, 0, 0);
    const int kkg = i * 16 + c;
#pragma unroll
    for (int mf = 0; mf < 4; ++mf)
#pragma unroll
      for (int r = 0; r < 4; ++r) {
        int mrow = mb + mf * 16 + lg * 4 + r;
        int trel = mrow >> 8, rw = mrow & 255;
        thxH[(((size_t)trel * 256 + rw) * 4 + wave) * 256 + kkg] =
            f2h(ac[mf][r] + bv);
      }
  }
}

// ---- Recurrent kernel: 256 WGs (1 row each) x 512 thr, 2 waves/SIMD.
// Wave (g,hh): 8 ntiles x 4 kt i8 frags (kt0,3 VGPR / kt1,2 AGPR).
// h state = 16-bit (hi/lo i8 planes, two MFMA chains, exact int combine).
// Broadcast-A from 512B Hq buffer; DPP scan; 2 barriers/step.
__global__ __launch_bounds__(NTHREADS, 2) void qlstm_rec(
    const uint* __restrict__ thxU,
    const int32x4* __restrict__ Whq,
    const float* __restrict__ sw,
    const float* __restrict__ temps,
    signed char* __restrict__ hGq, float* __restrict__ cG,
    float* __restrict__ out,
    int t0, int nsteps)
{
  __shared__ signed char Hq[512];             // h(t): hi plane [0,256), lo [256,512)
  __shared__ float RAW[4 * 264];              // raw cumprods [gate][kk]
  __shared__ __align__(16) float halfTot[4];  // half-0 totals per gate

  const int tid = threadIdx.x;
  const int wv = tid >> 6, lane = tid & 63;
  const int g = wv >> 1, hh = wv & 1;
  const int lg = lane >> 4;
  const int row = blockIdx.x;
  const int ukk = tid & 255, e = tid >> 8;

  // ---- Wh frags: kt0,3 -> VGPR (builtin bookends), kt1,2 -> AGPR (asm) ----
  int32x4 w0[8], w3[8], wa1[8], wa2[8];
#pragma unroll
  for (int j = 0; j < 8; ++j) {
    const size_t nb = (size_t)(g * 16 + hh * 8 + j) * 4;
    w0[j]  = Whq[(nb + 0) * 64 + lane];
    wa1[j] = Whq[(nb + 1) * 64 + lane];
    wa2[j] = Whq[(nb + 2) * 64 + lane];
    w3[j]  = Whq[(nb + 3) * 64 + lane];
  }
  const float2 sc = *(const float2*)&sw[g * 256 + hh * 128 + lane * 2];
  const float it0 = frcp(temps[0]), it1 = frcp(temps[1]);
  const float it2 = frcp(temps[2]), it3 = frcp(temps[3]);

  // ---- init h / c ----
  float creg = 0.f;
  {
    signed char hvh = 0, hvl = 0;
    if (t0 != 0) {
      hvh = hGq[(size_t)row * 256 + ukk];
      hvl = hGq[65536 + (size_t)row * 256 + ukk];
      creg = cG[(size_t)row * 256 + ukk];
    }
    if (e == 0) { Hq[ukk] = hvh; Hq[256 + ukk] = hvl; }
  }
  __syncthreads();

  const size_t txbase = ((size_t)row * 4 + g) * 128 + hh * 64 + lane;
  uint tx = thxU[txbase];
  float hprev = 0.f, cprev = 0.f;

#pragma unroll 1
  for (int ts = 0; ts < nsteps; ++ts) {
    const int t = t0 + ts;

    // deferred h(t-1) store: drains during GEMM, not at a barrier
    if (ts > 0 && e == 0)
      out[((size_t)(t - 1) * BATCH + row) * DHID + ukk] = hprev;

    // prefetch theta_x(ts+1)
    const int tsn = (ts + 1 < nsteps) ? ts + 1 : ts;
    const uint txn = thxU[(size_t)tsn * TXSTEPU + txbase];

    // A-frags: broadcast reads (all M rows = replicas for free)
    int32x4 afh0 = *(const int32x4*)&Hq[lg * 16];
    int32x4 afh1 = *(const int32x4*)&Hq[lg * 16 + 64];
    int32x4 afh2 = *(const int32x4*)&Hq[lg * 16 + 128];
    int32x4 afh3 = *(const int32x4*)&Hq[lg * 16 + 192];
    int32x4 afl0 = *(const int32x4*)&Hq[256 + lg * 16];
    int32x4 afl1 = *(const int32x4*)&Hq[256 + lg * 16 + 64];
    int32x4 afl2 = *(const int32x4*)&Hq[256 + lg * 16 + 128];
    int32x4 afl3 = *(const int32x4*)&Hq[256 + lg * 16 + 192];

    // GEMM: two i8 chains (hi, lo), shared W frags, 64 MFMA/wave
    const int32x4 zq = {0, 0, 0, 0};
    int32x4 acch[8], accl[8];
#pragma unroll
    for (int j = 0; j < 8; ++j)
      acch[j] = __builtin_amdgcn_mfma_i32_16x16x64_i8(afh0, w0[j], zq, 0, 0, 0);
#pragma unroll
    for (int j = 0; j < 8; ++j)
      accl[j] = __builtin_amdgcn_mfma_i32_16x16x64_i8(afl0, w0[j], zq, 0, 0, 0);
#pragma unroll
    for (int j = 0; j < 8; ++j) mfma_i8_a(acch[j], afh1, wa1[j]);
#pragma unroll
    for (int j = 0; j < 8; ++j) mfma_i8_a(accl[j], afl1, wa1[j]);
#pragma unroll
    for (int j = 0; j < 8; ++j) mfma_i8_a(acch[j], afh2, wa2[j]);
#pragma unroll
    for (int j = 0; j < 8; ++j) mfma_i8_a(accl[j], afl2, wa2[j]);
#pragma unroll
    for (int j = 0; j < 8; ++j)
      acch[j] = __builtin_amdgcn_mfma_i32_16x16x64_i8(afh3, w3[j], acch[j], 0, 0, 0);
#pragma unroll
    for (int j = 0; j < 8; ++j)
      accl[j] = __builtin_amdgcn_mfma_i32_16x16x64_i8(afl3, w3[j], accl[j], 0, 0, 0);

    // select this lane's kk pair {2L,2L+1}, exact int combine, dequant, cos
    int ah0 = (lg < 2) ? (lg == 0 ? acch[0][0] : acch[2][0])
                       : (lg == 2 ? acch[4][0] : acch[6][0]);
    int ah1 = (lg < 2) ? (lg == 0 ? acch[1][0] : acch[3][0])
                       : (lg == 2 ? acch[5][0] : acch[7][0]);
    int al0 = (lg < 2) ? (lg == 0 ? accl[0][0] : accl[2][0])
                       : (lg == 2 ? accl[4][0] : accl[6][0]);
    int al1 = (lg < 2) ? (lg == 0 ? accl[1][0] : accl[3][0])
                       : (lg == 2 ? accl[5][0] : accl[7][0]);
    float th0 = (float)((ah0 << 8) + al0) * sc.x;
    float th1 = (float)((ah1 << 8) + al1) * sc.y;
    float c0 = __cosf(h2f((ushort)(tx & 0xffffu)) + th0);
    float c1 = __cosf(h2f((ushort)(tx >> 16)) + th1);
    float pair = c0 * c1;

    // DPP 64-lane inclusive multiply-scan (row_shr 1,2,4,8 + bcast15/31)
    float s = pair;
    s *= DPPM(s, 0x111, 0xf);
    s *= DPPM(s, 0x112, 0xf);
    s *= DPPM(s, 0x114, 0xf);
    s *= DPPM(s, 0x118, 0xf);
    s *= DPPM(s, 0x142, 0xa);
    s *= DPPM(s, 0x143, 0xc);
    const float incl = s;
    float prefix = __shfl_up(incl, 1);
    if (lane == 0) prefix = 1.f;

    // publish raw cumprods (half-local); halfTot correction done in update
    float2 rw; rw.x = prefix * c0; rw.y = incl;
    *(float2*)&RAW[g * 264 + hh * 128 + lane * 2] = rw;
    if (hh == 0 && lane == 63) halfTot[g] = incl;
    __syncthreads();   // B1: RAW + halfTot complete

    // update: all 512 threads (e=0/1 duplicate compute; e=0 does I/O)
    {
      float r_f = RAW[0 * 264 + ukk], r_i = RAW[1 * 264 + ukk];
      float r_g = RAW[2 * 264 + ukk], r_o = RAW[3 * 264 + ukk];
      if (ukk >= 128) {                       // wave-uniform branch
        float4 hT = *(const float4*)halfTot;  // broadcast b128
        r_f *= hT.x; r_i *= hT.y; r_g *= hT.z; r_o *= hT.w;
      }
      float fv = fast_sigmoid(r_f * it0);
      float iv = fast_sigmoid(r_i * it1);
      float gv = fast_tanh  (r_g * it2);
      float ov = fast_sigmoid(r_o * it3);
      float cn = fv * creg + iv * gv;
      creg = cn;
      float h = ov * fast_tanh(cn);
      if (e == 0) {
        int q = __float2int_rn(h * HSCALE);
        int lo = ((q + 128) & 255) - 128;
        int hi = (q - lo) >> 8;
        Hq[ukk] = (signed char)hi;
        Hq[256 + ukk] = (signed char)lo;
        hprev = h; cprev = cn;
      }
    }
    __syncthreads();   // B2: Hq(t+1) complete

    tx = txn;
  }

  // epilogue: final h store + hx/cx + chunk state
  if (e == 0) {
    const int tl = t0 + nsteps - 1;
    out[((size_t)tl * BATCH + row) * DHID + ukk] = hprev;
    if (tl == T_STEPS - 1) {
      out[((size_t)T_STEPS * BATCH + row) * DHID + ukk] = hprev;
      out[((size_t)T_STEPS * BATCH + BATCH + row) * DHID + ukk] = cprev;
    }
    int q = __float2int_rn(hprev * HSCALE);
    int lo = ((q + 128) & 255) - 128;
    int hi = (q - lo) >> 8;
    hGq[(size_t)row * 256 + ukk] = (signed char)hi;
    hGq[65536 + (size_t)row * 256 + ukk] = (signed char)lo;
    cG[(size_t)row * 256 + ukk] = cprev;
  }
}

extern "C" void kernel_launch(void* const* d_in, const int* in_sizes, int n_in,
                              void* d_out, int out_size, void* d_ws, size_t ws_size,
                              hipStream_t stream) {
  (void)in_sizes; (void)n_in; (void)out_size;
  const float* x   = (const float*)d_in[0];
  const float* Wf  = (const float*)d_in[1];
  const float* bf_ = (const float*)d_in[2];
  const float* tf_ = (const float*)d_in[3];
  const float* Wi  = (const float*)d_in[4];
  const float* bi_ = (const float*)d_in[5];
  const float* ti_ = (const float*)d_in[6];
  const float* Wg  = (const float*)d_in[7];
  const float* bg_ = (const float*)d_in[8];
  const float* tg_ = (const float*)d_in[9];
  const float* Wo  = (const float*)d_in[10];
  const float* bo_ = (const float*)d_in[11];
  const float* to_ = (const float*)d_in[12];

  char* ws = (char*)d_ws;
  bf16_t*      Wxp   = (bf16_t*)(ws + WS_WXP);
  signed char* Whq   = (signed char*)(ws + WS_WHQ);
  float*       sw    = (float*)(ws + WS_SW);
  float*       rq    = (float*)(ws + WS_RQ);
  float*       bias  = (float*)(ws + WS_BIAS);
  float*       temps = (float*)(ws + WS_TMP);
  signed char* hGq   = (signed char*)(ws + WS_HGQ);
  float*       cG    = (float*)(ws + WS_CG);
  ushort*      thxH  = (ushort*)(ws + WS_THX);

  size_t avail = ws_size > (size_t)(2u << 20) ? ws_size - (size_t)(2u << 20) : 0;
  int CH = 4;
  const int cands[6] = {128, 64, 32, 16, 8, 4};
  for (int ci = 0; ci < 6; ++ci)
    if ((size_t)cands[ci] * 512 * 1024 <= avail) { CH = cands[ci]; break; }

  hipLaunchKernelGGL(k_scales, dim3(4), dim3(256), 0, stream,
                     Wf, Wi, Wg, Wo, sw, rq);
  hipLaunchKernelGGL(k_packx, dim3(128), dim3(256), 0, stream,
                     Wf, Wi, Wg, Wo, bf_, bi_, bg_, bo_, tf_, ti_, tg_, to_,
                     Wxp, bias, temps);
  hipLaunchKernelGGL(k_packh, dim3(64), dim3(256), 0, stream,
                     Wf, Wi, Wg, Wo, rq, Whq);

  for (int c0 = 0; c0 < T_STEPS; c0 += CH) {
    hipLaunchKernelGGL(gemm_thx, dim3(CH * 4), dim3(256), 0, stream,
                       x + (size_t)c0 * BATCH * DIN, Wxp, bias, thxH);
    hipLaunchKernelGGL(qlstm_rec, dim3(NWG), dim3(NTHREADS), 0, stream,
                       (const uint*)thxH, (const int32x4*)Whq, sw, temps,
                       hGq, cG, (float*)d_out, c0, CH);
  }
}

// Round 15
// 814.304 us; speedup vs baseline: 1.3766x; 1.3719x over previous
//
#include <hip/hip_runtime.h>

#define T_STEPS 512
#define BATCH   256
#define DIN     256
#define DHID    256
#define NWG     256      // one WG per batch row
#define NTHREADS 512     // 8 waves: wave = (gate, n-half), 2 waves/SIMD

typedef short bf16_t;
typedef __attribute__((ext_vector_type(4))) short short4v;
typedef __attribute__((ext_vector_type(8))) short short8;
typedef __attribute__((ext_vector_type(4))) float f32x4;
typedef __attribute__((ext_vector_type(4))) int int32x4;
typedef unsigned int uint;
typedef unsigned short ushort;

// ---- workspace layout (bytes) ----
#define WS_WXP  0u                   // 512 KB bf16 Wx frags
#define WS_WHQ  (512u << 10)         // 256 KB i8 Wh frags
#define WS_SW   (768u << 10)         // 4 KB f32 sW[1024] (amax/(127*32512))
#define WS_RQ   (772u << 10)         // 4 KB f32 rq[1024] (127/amax)
#define WS_BIAS (776u << 10)         // 4 KB
#define WS_TMP  (780u << 10)         // 16 B
#define WS_HGQ  (784u << 10)         // 128 KB h state: hi plane + lo plane
#define WS_CG   (912u << 10)         // 256 KB f32 c state
#define WS_THX  (2u << 20)           // CH*512KB theta_x chunk (f16)

#define TXSTEPU 131072               // uints per t: 256 rows x 4 gates x 128
#define HSCALE  32512.f              // 127*256

__device__ inline short f2bf(float f) {
  union { float f; uint u; } v; v.f = f;
  uint r = (v.u + 0x7FFFu + ((v.u >> 16) & 1u)) >> 16;
  return (short)r;
}
__device__ inline ushort f2h(float f) {
  union { _Float16 h; ushort u; } v; v.h = (_Float16)f; return v.u;
}
__device__ inline float h2f(ushort u) {
  union { _Float16 h; ushort u; } v; v.u = u; return (float)v.h;
}
__device__ inline float frcp(float x) { return __builtin_amdgcn_rcpf(x); }
__device__ inline float fast_sigmoid(float x) { return frcp(1.f + __expf(-x)); }
__device__ inline float fast_tanh(float x) {
  float ax = fabsf(x);
  float e = __expf(2.f * ax);              // inf-safe
  float r = 1.f - 2.f * frcp(e + 1.f);
  return copysignf(r, x);
}

// asm i8 MFMA with B pinned in AGPRs (r5..r14-proven: chains bookended by
// builtins so the compiler guards VALU<->MFMA hazards).
__device__ inline void mfma_i8_a(int32x4& acc, int32x4 a, int32x4 b) {
  asm("v_mfma_i32_16x16x64_i8 %0, %1, %2, %0"
      : "+v"(acc) : "v"(a), "a"(b));
}

// DPP fetch with multiplicative identity for invalid/masked lanes.
#define DPPM(x, ctrl, rmask)                                                  \
  __int_as_float(__builtin_amdgcn_update_dpp(                                 \
      0x3f800000, __float_as_int(x), (ctrl), (rmask), 0xf, false))

// ---- per-neuron amax scales for Wh (k in [256,512)) ----
// sw = amax/(127*32512): dequant for W (x127/amax) and h16 (x32512) quant.
__global__ __launch_bounds__(256) void k_scales(
    const float* __restrict__ Wf, const float* __restrict__ Wi,
    const float* __restrict__ Wg, const float* __restrict__ Wo,
    float* __restrict__ sw, float* __restrict__ rq)
{
  int n = blockIdx.x * 256 + threadIdx.x;       // 0..1023
  int gate = n >> 8, nrow = n & 255;
  const float* W = gate == 0 ? Wf : gate == 1 ? Wi : gate == 2 ? Wg : Wo;
  const float4* row = (const float4*)(W + (size_t)nrow * 512 + 256);
  float amax = 0.f;
#pragma unroll 4
  for (int k = 0; k < 64; ++k) {
    float4 v = row[k];
    amax = fmaxf(amax, fmaxf(fmaxf(fabsf(v.x), fabsf(v.y)),
                             fmaxf(fabsf(v.z), fabsf(v.w))));
  }
  sw[n] = amax / (127.f * HSCALE);
  rq[n] = amax > 0.f ? 127.f / amax : 0.f;
}

// ---- pack Wx (k<256) into bf16 MFMA B-frag order + bias + temps ----
__global__ __launch_bounds__(256) void k_packx(
    const float* __restrict__ Wf, const float* __restrict__ Wi,
    const float* __restrict__ Wg, const float* __restrict__ Wo,
    const float* __restrict__ bf_, const float* __restrict__ bi_,
    const float* __restrict__ bg_, const float* __restrict__ bo_,
    const float* __restrict__ tf_, const float* __restrict__ ti_,
    const float* __restrict__ tg_, const float* __restrict__ to_,
    bf16_t* __restrict__ Wxp, float* __restrict__ bias,
    float* __restrict__ temps)
{
  int tid = blockIdx.x * 256 + threadIdx.x;     // 0..32767
  int nt = tid >> 9;
  int kt = (tid >> 6) & 7;
  int lane = tid & 63;
  int n = nt * 16 + (lane & 15);
  int gate = n >> 8, nrow = n & 255;
  int k = kt * 32 + (lane >> 4) * 8;
  const float* W = gate == 0 ? Wf : gate == 1 ? Wi : gate == 2 ? Wg : Wo;
  const float* src = W + (size_t)nrow * 512 + k;
  short8 d;
#pragma unroll
  for (int j = 0; j < 8; ++j) d[j] = f2bf(src[j]);
  *(short8*)(Wxp + (size_t)tid * 8) = d;

  if (tid < 1024) {
    int g2 = tid >> 8;
    const float* bs = g2 == 0 ? bf_ : g2 == 1 ? bi_ : g2 == 2 ? bg_ : bo_;
    bias[tid] = bs[tid & 255];
  }
  if (tid < 4) {
    const float* ts = tid == 0 ? tf_ : tid == 1 ? ti_ : tid == 2 ? tg_ : to_;
    temps[tid] = ts[0];
  }
}

// ---- pack Wh into i8 16x16x64 B-frag order with scan-friendly n-perm ----
// ntile nt = g*16 + hh*8 + j, frag col fc: neuron kk(within gate) =
// hh*128 + (j>>1)*32 + fc*2 + (j&1)  -> rec lane L holds kk pair {2L, 2L+1}.
__global__ __launch_bounds__(256) void k_packh(
    const float* __restrict__ Wf, const float* __restrict__ Wi,
    const float* __restrict__ Wg, const float* __restrict__ Wo,
    const float* __restrict__ rq, signed char* __restrict__ Whq)
{
  int tid = blockIdx.x * 256 + threadIdx.x;     // 0..16383
  int nt = tid >> 8;
  int kt = (tid >> 6) & 3;
  int lane = tid & 63;
  int fc = lane & 15;
  int gate = nt >> 4, hh = (nt >> 3) & 1, j = nt & 7;
  int n = gate * 256 + hh * 128 + ((j >> 1) << 5) + fc * 2 + (j & 1);
  int nrow = n & 255;
  int k0 = 256 + kt * 64 + (lane >> 4) * 16;
  const float* W = gate == 0 ? Wf : gate == 1 ? Wi : gate == 2 ? Wg : Wo;
  const float* src = W + (size_t)nrow * 512 + k0;
  float r = rq[n];
  union { signed char b[16]; int32x4 v; } pk;
#pragma unroll
  for (int jj = 0; jj < 16; ++jj) {
    int qi = __float2int_rn(src[jj] * r);
    qi = qi > 127 ? 127 : (qi < -127 ? -127 : qi);
    pk.b[jj] = (signed char)qi;
  }
  *(int32x4*)(Whq + (size_t)tid * 16) = pk.v;
}

// ---- theta_x GEMM; store f16 ushort[t][row256][gate4][kk256] ----
__global__ __launch_bounds__(256, 1) void gemm_thx(
    const float* __restrict__ x,        // chunk slice [CH*256, 256]
    const bf16_t* __restrict__ Wxp,
    const float* __restrict__ bias,
    ushort* __restrict__ thxH)
{
  __shared__ bf16_t Ax[64 * 256];       // XOR-swizzled, 512 B row stride
  const int tid = threadIdx.x;
  const int wave = tid >> 6, lane = tid & 63;
  const int lg = lane >> 4, c = lane & 15;
  const int mb = blockIdx.x * 64;

#pragma unroll
  for (int rep = 0; rep < 16; ++rep) {
    int idx = tid + rep * 256;
    int row = idx >> 6, c4f = (idx & 63) * 4;
    float4 v = *(const float4*)(x + (size_t)(mb + row) * 256 + c4f);
    short4v d;
    d[0] = f2bf(v.x); d[1] = f2bf(v.y); d[2] = f2bf(v.z); d[3] = f2bf(v.w);
    *(short4v*)((char*)Ax + row * 512 + ((c4f * 2) ^ ((row & 7) << 4))) = d;
  }
  __syncthreads();

  short8 af[4][8];
#pragma unroll
  for (int mf = 0; mf < 4; ++mf)
#pragma unroll
    for (int kt = 0; kt < 8; ++kt) {
      int row = mf * 16 + (lane & 15);
      int kb = kt * 64 + (lane >> 4) * 16;
      af[mf][kt] = *(const short8*)((char*)Ax + row * 512 + (kb ^ ((row & 7) << 4)));
    }

#pragma unroll 1
  for (int i = 0; i < 16; ++i) {
    short8 wfr[8];
#pragma unroll
    for (int kt = 0; kt < 8; ++kt)
      wfr[kt] = *(const short8*)(Wxp + ((((size_t)(wave * 16 + i)) * 8 + kt) * 64 + lane) * 8);
    float bv = bias[wave * 256 + i * 16 + c];
    f32x4 ac[4];
#pragma unroll
    for (int mf = 0; mf < 4; ++mf) ac[mf] = (f32x4){0.f, 0.f, 0.f, 0.f};
#pragma unroll
    for (int kt = 0; kt < 8; ++kt)
#pragma unroll
      for (int mf = 0; mf < 4; ++mf)
        ac[mf] = __builtin_amdgcn_mfma_f32_16x16x32_bf16(af[mf][kt], wfr[kt], ac[mf], 0, 0, 0);
    const int kkg = i * 16 + c;
#pragma unroll
    for (int mf = 0; mf < 4; ++mf)
#pragma unroll
      for (int r = 0; r < 4; ++r) {
        int mrow = mb + mf * 16 + lg * 4 + r;
        int trel = mrow >> 8, rw = mrow & 255;
        thxH[(((size_t)trel * 256 + rw) * 4 + wave) * 256 + kkg] =
            f2h(ac[mf][r] + bv);
      }
  }
}

// ---- Recurrent kernel: 256 WGs (1 row each) x 512 thr, 2 waves/SIMD.
// Wave (g,hh): 8 ntiles x 4 kt i8 frags (kt0,3 VGPR / kt1,2 AGPR).
// h state = 16-bit via hi/lo i8 planes folded into ONE MFMA chain:
// even A-rows (lane&1==0) carry the hi plane, odd rows the lo plane, so
// D-row lg*4 = hi dot and D-row lg*4+1 = lo dot of the same neuron —
// 32 MFMA/wave total. Broadcast-A; DPP scan; 2 barriers/step.
__global__ __launch_bounds__(NTHREADS, 2) void qlstm_rec(
    const uint* __restrict__ thxU,
    const int32x4* __restrict__ Whq,
    const float* __restrict__ sw,
    const float* __restrict__ temps,
    signed char* __restrict__ hGq, float* __restrict__ cG,
    float* __restrict__ out,
    int t0, int nsteps)
{
  __shared__ signed char Hq[512];             // h(t): hi plane [0,256), lo [256,512)
  __shared__ float RAW[4 * 264];              // raw cumprods [gate][kk]
  __shared__ __align__(16) float halfTot[4];  // half-0 totals per gate

  const int tid = threadIdx.x;
  const int wv = tid >> 6, lane = tid & 63;
  const int g = wv >> 1, hh = wv & 1;
  const int lg = lane >> 4;
  const int row = blockIdx.x;
  const int ukk = tid & 255, e = tid >> 8;
  const int hbase = (lane & 1) * 256;         // A-row parity -> plane select

  // ---- Wh frags: kt0,3 -> VGPR (builtin bookends), kt1,2 -> AGPR (asm) ----
  int32x4 w0[8], w3[8], wa1[8], wa2[8];
#pragma unroll
  for (int j = 0; j < 8; ++j) {
    const size_t nb = (size_t)(g * 16 + hh * 8 + j) * 4;
    w0[j]  = Whq[(nb + 0) * 64 + lane];
    wa1[j] = Whq[(nb + 1) * 64 + lane];
    wa2[j] = Whq[(nb + 2) * 64 + lane];
    w3[j]  = Whq[(nb + 3) * 64 + lane];
  }
  const float2 sc = *(const float2*)&sw[g * 256 + hh * 128 + lane * 2];
  const float it0 = frcp(temps[0]), it1 = frcp(temps[1]);
  const float it2 = frcp(temps[2]), it3 = frcp(temps[3]);

  // ---- init h / c ----
  float creg = 0.f;
  {
    signed char hvh = 0, hvl = 0;
    if (t0 != 0) {
      hvh = hGq[(size_t)row * 256 + ukk];
      hvl = hGq[65536 + (size_t)row * 256 + ukk];
      creg = cG[(size_t)row * 256 + ukk];
    }
    if (e == 0) { Hq[ukk] = hvh; Hq[256 + ukk] = hvl; }
  }
  __syncthreads();

  const size_t txbase = ((size_t)row * 4 + g) * 128 + hh * 64 + lane;
  uint tx = thxU[txbase];
  float hprev = 0.f, cprev = 0.f;

#pragma unroll 1
  for (int ts = 0; ts < nsteps; ++ts) {
    const int t = t0 + ts;

    // deferred h(t-1) store: drains during GEMM, not at a barrier
    if (ts > 0 && e == 0)
      out[((size_t)(t - 1) * BATCH + row) * DHID + ukk] = hprev;

    // prefetch theta_x(ts+1)
    const int tsn = (ts + 1 < nsteps) ? ts + 1 : ts;
    const uint txn = thxU[(size_t)tsn * TXSTEPU + txbase];

    // A-frags: plane by A-row parity (even=hi, odd=lo); broadcast within plane
    int32x4 af0 = *(const int32x4*)&Hq[hbase + lg * 16];
    int32x4 af1 = *(const int32x4*)&Hq[hbase + lg * 16 + 64];
    int32x4 af2 = *(const int32x4*)&Hq[hbase + lg * 16 + 128];
    int32x4 af3 = *(const int32x4*)&Hq[hbase + lg * 16 + 192];

    // GEMM: ONE i8 chain, 32 MFMA/wave; D-row lg*4 = hi, lg*4+1 = lo
    const int32x4 zq = {0, 0, 0, 0};
    int32x4 acc[8];
#pragma unroll
    for (int j = 0; j < 8; ++j)
      acc[j] = __builtin_amdgcn_mfma_i32_16x16x64_i8(af0, w0[j], zq, 0, 0, 0);
#pragma unroll
    for (int j = 0; j < 8; ++j) mfma_i8_a(acc[j], af1, wa1[j]);
#pragma unroll
    for (int j = 0; j < 8; ++j) mfma_i8_a(acc[j], af2, wa2[j]);
#pragma unroll
    for (int j = 0; j < 8; ++j)
      acc[j] = __builtin_amdgcn_mfma_i32_16x16x64_i8(af3, w3[j], acc[j], 0, 0, 0);

    // select this lane's kk pair {2L,2L+1}: j-pair by lg; hi=reg0, lo=reg1
    int ah0 = (lg < 2) ? (lg == 0 ? acc[0][0] : acc[2][0])
                       : (lg == 2 ? acc[4][0] : acc[6][0]);
    int al0 = (lg < 2) ? (lg == 0 ? acc[0][1] : acc[2][1])
                       : (lg == 2 ? acc[4][1] : acc[6][1]);
    int ah1 = (lg < 2) ? (lg == 0 ? acc[1][0] : acc[3][0])
                       : (lg == 2 ? acc[5][0] : acc[7][0]);
    int al1 = (lg < 2) ? (lg == 0 ? acc[1][1] : acc[3][1])
                       : (lg == 2 ? acc[5][1] : acc[7][1]);
    float th0 = (float)((ah0 << 8) + al0) * sc.x;
    float th1 = (float)((ah1 << 8) + al1) * sc.y;
    float c0 = __cosf(h2f((ushort)(tx & 0xffffu)) + th0);
    float c1 = __cosf(h2f((ushort)(tx >> 16)) + th1);
    float pair = c0 * c1;

    // DPP 64-lane inclusive multiply-scan (row_shr 1,2,4,8 + bcast15/31)
    float s = pair;
    s *= DPPM(s, 0x111, 0xf);
    s *= DPPM(s, 0x112, 0xf);
    s *= DPPM(s, 0x114, 0xf);
    s *= DPPM(s, 0x118, 0xf);
    s *= DPPM(s, 0x142, 0xa);
    s *= DPPM(s, 0x143, 0xc);
    const float incl = s;
    float prefix = __shfl_up(incl, 1);
    if (lane == 0) prefix = 1.f;

    // publish raw cumprods (half-local); halfTot correction done in update
    float2 rw; rw.x = prefix * c0; rw.y = incl;
    *(float2*)&RAW[g * 264 + hh * 128 + lane * 2] = rw;
    if (hh == 0 && lane == 63) halfTot[g] = incl;
    __syncthreads();   // B1: RAW + halfTot complete

    // update: all 512 threads (e=0/1 duplicate compute; e=0 does I/O)
    {
      float r_f = RAW[0 * 264 + ukk], r_i = RAW[1 * 264 + ukk];
      float r_g = RAW[2 * 264 + ukk], r_o = RAW[3 * 264 + ukk];
      if (ukk >= 128) {                       // wave-uniform branch
        float4 hT = *(const float4*)halfTot;  // broadcast b128
        r_f *= hT.x; r_i *= hT.y; r_g *= hT.z; r_o *= hT.w;
      }
      float fv = fast_sigmoid(r_f * it0);
      float iv = fast_sigmoid(r_i * it1);
      float gv = fast_tanh  (r_g * it2);
      float ov = fast_sigmoid(r_o * it3);
      float cn = fv * creg + iv * gv;
      creg = cn;
      float h = ov * fast_tanh(cn);
      if (e == 0) {
        int q = __float2int_rn(h * HSCALE);
        int lo = ((q + 128) & 255) - 128;
        int hi = (q - lo) >> 8;
        Hq[ukk] = (signed char)hi;
        Hq[256 + ukk] = (signed char)lo;
        hprev = h; cprev = cn;
      }
    }
    __syncthreads();   // B2: Hq(t+1) complete

    tx = txn;
  }

  // epilogue: final h store + hx/cx + chunk state
  if (e == 0) {
    const int tl = t0 + nsteps - 1;
    out[((size_t)tl * BATCH + row) * DHID + ukk] = hprev;
    if (tl == T_STEPS - 1) {
      out[((size_t)T_STEPS * BATCH + row) * DHID + ukk] = hprev;
      out[((size_t)T_STEPS * BATCH + BATCH + row) * DHID + ukk] = cprev;
    }
    int q = __float2int_rn(hprev * HSCALE);
    int lo = ((q + 128) & 255) - 128;
    int hi = (q - lo) >> 8;
    hGq[(size_t)row * 256 + ukk] = (signed char)hi;
    hGq[65536 + (size_t)row * 256 + ukk] = (signed char)lo;
    cG[(size_t)row * 256 + ukk] = cprev;
  }
}

extern "C" void kernel_launch(void* const* d_in, const int* in_sizes, int n_in,
                              void* d_out, int out_size, void* d_ws, size_t ws_size,
                              hipStream_t stream) {
  (void)in_sizes; (void)n_in; (void)out_size;
  const float* x   = (const float*)d_in[0];
  const float* Wf  = (const float*)d_in[1];
  const float* bf_ = (const float*)d_in[2];
  const float* tf_ = (const float*)d_in[3];
  const float* Wi  = (const float*)d_in[4];
  const float* bi_ = (const float*)d_in[5];
  const float* ti_ = (const float*)d_in[6];
  const float* Wg  = (const float*)d_in[7];
  const float* bg_ = (const float*)d_in[8];
  const float* tg_ = (const float*)d_in[9];
  const float* Wo  = (const float*)d_in[10];
  const float* bo_ = (const float*)d_in[11];
  const float* to_ = (const float*)d_in[12];

  char* ws = (char*)d_ws;
  bf16_t*      Wxp   = (bf16_t*)(ws + WS_WXP);
  signed char* Whq   = (signed char*)(ws + WS_WHQ);
  float*       sw    = (float*)(ws + WS_SW);
  float*       rq    = (float*)(ws + WS_RQ);
  float*       bias  = (float*)(ws + WS_BIAS);
  float*       temps = (float*)(ws + WS_TMP);
  signed char* hGq   = (signed char*)(ws + WS_HGQ);
  float*       cG    = (float*)(ws + WS_CG);
  ushort*      thxH  = (ushort*)(ws + WS_THX);

  size_t avail = ws_size > (size_t)(2u << 20) ? ws_size - (size_t)(2u << 20) : 0;
  int CH = 4;
  const int cands[6] = {128, 64, 32, 16, 8, 4};
  for (int ci = 0; ci < 6; ++ci)
    if ((size_t)cands[ci] * 512 * 1024 <= avail) { CH = cands[ci]; break; }

  hipLaunchKernelGGL(k_scales, dim3(4), dim3(256), 0, stream,
                     Wf, Wi, Wg, Wo, sw, rq);
  hipLaunchKernelGGL(k_packx, dim3(128), dim3(256), 0, stream,
                     Wf, Wi, Wg, Wo, bf_, bi_, bg_, bo_, tf_, ti_, tg_, to_,
                     Wxp, bias, temps);
  hipLaunchKernelGGL(k_packh, dim3(64), dim3(256), 0, stream,
                     Wf, Wi, Wg, Wo, rq, Whq);

  for (int c0 = 0; c0 < T_STEPS; c0 += CH) {
    hipLaunchKernelGGL(gemm_thx, dim3(CH * 4), dim3(256), 0, stream,
                       x + (size_t)c0 * BATCH * DIN, Wxp, bias, thxH);
    hipLaunchKernelGGL(qlstm_rec, dim3(NWG), dim3(NTHREADS), 0, stream,
                       (const uint*)thxH, (const int32x4*)Whq, sw, temps,
                       hGq, cG, (float*)d_out, c0, CH);
  }
}